// Round 9
// baseline (2871.419 us; speedup 1.0000x reference)
//
#include <hip/hip_runtime.h>
#include <cstdint>
#include <cstddef>

// B=32, S=512, I=256, H=512, E=1024, NH=16, HD=64
// Structural collapse (verified): only attention head 15 at s in [496,512)
// reaches the FC head; backward LSTM needs only its first 16 steps; Wo/Wfc
// fold to w_eff; w_eff-contracted Wv folds to wv2.
//
// Round 9: kill the post-detect tail. R8 taught: (a) remaining 3.9e7 LDS
// conflicts live in the gates partial writes (8-way) and panel reads
// (PSTR=388 words = 4 mod 32), not the gather; (b) 260MB FETCH is intrinsic
// poll traffic (agent loads don't L2-cache). So this round removes the
// whole staging pipeline: (1) per-lane direct global->reg A-fragments
// (sentinel-polled; lanes l16>=8 load dup rows l16&7 once, outputs
// discarded) -- panel LDS + S_a barrier gone; (2) gates stored as one v4f
// per (lane,nt) into [n][wave][b] layout (disjoint 4-bank spans, ~0
// conflict) read back as 4 scalars (2-way, free); (3) gates double-buffered
// by t&1 -> ONE barrier per step. Exchange protocol, topology, numerics
// unchanged from the 1853us baseline.

typedef _Float16 v8h __attribute__((ext_vector_type(8)));
typedef float    v4f __attribute__((ext_vector_type(4)));
typedef unsigned long long u64;
struct u64x2 { u64 a, b; };

#define AT_LD(p)     __hip_atomic_load((p), __ATOMIC_RELAXED, __HIP_MEMORY_SCOPE_AGENT)
#define AT_ST(p, v)  __hip_atomic_store((p), (v), __ATOMIC_RELAXED, __HIP_MEMORY_SCOPE_AGENT)

// ---- workspace layout (bytes) ----
static constexpr size_t OFF_CNT   = 0;        // 3 x u32: lstm-done, -, epi-done
static constexpr size_t OFF_LOGIT = 256;      // 32 f32
static constexpr size_t OFF_BEFF  = 512;      // 1 f32
static constexpr size_t OFF_WEFF  = 1024;     // 1024 f32
static constexpr size_t OFF_HF    = 8192;     // h_f[513][32][512] f16 (slot = s+1)
static constexpr size_t HF_BYTES  = 513ull*32768;
static constexpr size_t OFF_HB    = OFF_HF + HF_BYTES;   // h_b[17][32][512] f16
static constexpr size_t HB_BYTES  = 17ull*32768;
static constexpr size_t OFF_WHHF  = OFF_HB + HB_BYTES;   // 2048x512 f16
static constexpr size_t OFF_WIHF  = OFF_WHHF + 2048ull*512*2;
static constexpr size_t OFF_WHHB  = OFF_WIHF + 2048ull*256*2;
static constexpr size_t OFF_WIHB  = OFF_WHHB + 2048ull*512*2;
static constexpr size_t OFF_WKT   = OFF_WIHB + 2048ull*256*2;   // 1024x1024 f16
static constexpr size_t OFF_WQT   = OFF_WKT + 1024ull*1024*2;   // 1024x64 f16
static constexpr size_t OFF_WV2   = OFF_WQT + 1024ull*64*2;     // 16*1024*16 f32
static constexpr size_t OFF_CV    = OFF_WV2 + 16ull*1024*16*4;  // 256 f32
// total ~25.7 MiB

static constexpr int GSTR    = 68;                  // gates row stride (f32 words)
static constexpr int GBUF_W  = 64*GSTR;             // one gates buffer (words)
static constexpr int DYN_LDS = 2*GBUF_W*4;          // 34816 B (epilogue needs 26.2KB)

__device__ __forceinline__ bool has_ffff(u64 w) {
    return ((w & 0xFFFFull) == 0xFFFFull) ||
           (((w >> 16) & 0xFFFFull) == 0xFFFFull) ||
           (((w >> 32) & 0xFFFFull) == 0xFFFFull) ||
           ((w >> 48) == 0xFFFFull);
}

// -------------------- prep kernels --------------------

__global__ void k_convert(const float* __restrict__ whhf, const float* __restrict__ wihf,
                          const float* __restrict__ whhb, const float* __restrict__ wihb,
                          char* __restrict__ ws)
{
    _Float16* o1 = (_Float16*)(ws + OFF_WHHF);
    _Float16* o2 = (_Float16*)(ws + OFF_WIHF);
    _Float16* o3 = (_Float16*)(ws + OFF_WHHB);
    _Float16* o4 = (_Float16*)(ws + OFF_WIHB);
    const int stride = gridDim.x * blockDim.x;
    for (int i = blockIdx.x*blockDim.x + threadIdx.x; i < 2048*512; i += stride) {
        o1[i] = (_Float16)whhf[i];
        o3[i] = (_Float16)whhb[i];
    }
    for (int i = blockIdx.x*blockDim.x + threadIdx.x; i < 2048*256; i += stride) {
        o2[i] = (_Float16)wihf[i];
        o4[i] = (_Float16)wihb[i];
    }
}

// weff[e2] += partial(Wfc . Wo[:,e2]); beff += partial(Wfc . bo) (+bfc once)
__global__ void k_weff(const float* __restrict__ Wfc, const float* __restrict__ Wo,
                       const float* __restrict__ bo, const float* __restrict__ bfc,
                       char* __restrict__ ws)
{
    float* weff = (float*)(ws + OFF_WEFF);
    float* beff = (float*)(ws + OFF_BEFF);
    const int bid = blockIdx.x;                 // 64 blocks
    const int e2 = (bid & 3)*256 + threadIdx.x;
    const int slab = bid >> 2;                  // 16 slabs of 64 e
    float a = 0.f;
    for (int e = slab*64; e < slab*64 + 64; ++e)
        a += Wfc[e] * Wo[(size_t)e*1024 + e2];
    atomicAdd(weff + e2, a);
    if ((bid & 3) == 0 && threadIdx.x < 64) {
        const int e = slab*64 + threadIdx.x;
        float b = Wfc[e]*bo[e];
        if (bid == 0 && threadIdx.x == 0) b += bfc[0];
        atomicAdd(beff, b);
    }
}

// wv2[(r*1024+e)*16+kh] = sum_hd weff[r*64+hd]*Wv[(kh*64+hd)*1024+e]; cv
__global__ void k_wv2(const float* __restrict__ Wv, const float* __restrict__ bv,
                      char* __restrict__ ws)
{
    const float* weff = (const float*)(ws + OFF_WEFF);
    float* wv2 = (float*)(ws + OFF_WV2);
    float* cv  = (float*)(ws + OFF_CV);
    const int bid = blockIdx.x;                 // 65 blocks
    if (bid < 64) {
        const int r = bid >> 2;
        const int e = (bid & 3)*256 + threadIdx.x;
        for (int kh = 0; kh < 16; ++kh) {
            float a = 0.f;
            for (int hd = 0; hd < 64; ++hd)
                a += weff[r*64 + hd] * Wv[((size_t)(kh*64 + hd))*1024 + e];
            wv2[((size_t)r*1024 + e)*16 + kh] = a;
        }
    } else {
        const int r2 = threadIdx.x >> 4, k2 = threadIdx.x & 15;
        float a = 0.f;
        for (int hd = 0; hd < 64; ++hd)
            a += weff[r2*64 + hd] * bv[k2*64 + hd];
        cv[threadIdx.x] = a;
    }
}

// WkT[e][j] = Wk[j][e], fp16
__global__ void k_tk(const float* __restrict__ Wk, char* __restrict__ ws)
{
    _Float16* WkT = (_Float16*)(ws + OFF_WKT);
    __shared__ float tile[32][33];
    const int jt = blockIdx.x & 31, et = blockIdx.x >> 5;   // 1024 blocks
    const int tx = threadIdx.x & 31, ty = threadIdx.x >> 5; // 32x8
    for (int i = 0; i < 4; ++i)
        tile[ty + 8*i][tx] = Wk[((size_t)(jt*32 + ty + 8*i))*1024 + et*32 + tx];
    __syncthreads();
    for (int i = 0; i < 4; ++i)
        WkT[((size_t)(et*32 + ty + 8*i))*1024 + jt*32 + tx] = (_Float16)tile[tx][ty + 8*i];
}

// WqT15[e][d] = Wq[960+d][e], fp16
__global__ void k_tq(const float* __restrict__ Wq, char* __restrict__ ws)
{
    _Float16* WqT = (_Float16*)(ws + OFF_WQT);
    const int gid = blockIdx.x*256 + threadIdx.x;  // 256 blocks
    const int d = gid & 63, e = gid >> 6;
    WqT[e*64 + d] = (_Float16)Wq[((size_t)(960 + d))*1024 + e];
}

// -------------------- main persistent kernel --------------------
// 128 WGs x 256 threads. group g = wgid>>5 (8 batches), colgroup = wgid&31
// (16 h-cols). Phase 0: bwd 16 steps; phase 1: fwd 512 steps. Sentinel
// data-polling, now per-lane directly into MFMA A-fragments. One barrier
// per step (gates double-buffered by t&1).

__global__ __launch_bounds__(256, 1)
void bilstm_main(const float* __restrict__ xg,
                 const float* __restrict__ b_f, const float* __restrict__ b_b,
                 const float* __restrict__ bq,  const float* __restrict__ bk,
                 char* __restrict__ ws, float* __restrict__ out)
{
    extern __shared__ char smem[];
    float* gates = (float*)smem;                 // [2][64][GSTR] f32

    const int tid  = threadIdx.x;
    const int wgid = blockIdx.x;
    const int wave = tid >> 6;
    const int lane = tid & 63;
    const int quad = lane >> 4;
    const int l16  = lane & 15;
    const int grp  = wgid >> 5;            // batch group (8 batches)
    const int col0 = (wgid & 31) * 16;

    unsigned* cnts  = (unsigned*)(ws + OFF_CNT);
    float*   logits = (float*)(ws + OFF_LOGIT);

    // activation role (tid < 128): batch b = tid>>4 in [0,8), col c = tid&15
    const int ac = tid & 15;
    const int ab = tid >> 4;

    // A-row batch for this lane (rows 8-15 duplicate 0-7; outputs discarded)
    const int bb = grp*8 + (l16 & 7);

    for (int phase = 0; phase < 2; ++phase) {
        const int dir     = phase == 0 ? 1 : 0;       // bwd first
        const int nsteps  = dir ? 16 : 512;
        char* hslab = ws + (dir ? OFF_HB : OFF_HF);
        const _Float16* whh = (const _Float16*)(ws + (dir ? OFF_WHHB : OFF_WHHF));
        const _Float16* wih = (const _Float16*)(ws + (dir ? OFF_WIHB : OFF_WIHF));
        const float* bias = dir ? b_b : b_f;

        // persistent B fragments: rows (gate nt, col l16) x K=768, wave = K-quarter
        v8h bfrag[4][6];
#pragma unroll
        for (int nt = 0; nt < 4; ++nt)
#pragma unroll
            for (int kk = 0; kk < 6; ++kk) {
                const int kb = (wave*6 + kk)*32 + quad*8;
                const int r  = nt*512 + col0 + l16;
                const _Float16* src = (kb < 512) ? (whh + (size_t)r*512 + kb)
                                                 : (wih + (size_t)r*256 + (kb - 512));
                bfrag[nt][kk] = *(const v8h*)src;
            }
        float bia[4];
#pragma unroll
        for (int g = 0; g < 4; ++g) bia[g] = bias[g*512 + col0 + ac];

        float cst = 0.f;

        for (int t = 0; t < nsteps; ++t) {
            const int s = dir ? (511 - t) : t;
            float* gbuf = gates + (t & 1)*GBUF_W;

            // ---- A fragments, direct to registers ----
            v8h af[6];
            // x part (kb >= 512): load once, no poll (uniform per wave/kk)
#pragma unroll
            for (int kk = 0; kk < 6; ++kk) {
                const int kb = (wave*6 + kk)*32 + quad*8;
                if (kb >= 512) {
                    const float* xp = xg + ((size_t)bb*512 + s)*256 + (kb - 512);
                    const float4 x0 = *(const float4*)(xp);
                    const float4 x1 = *(const float4*)(xp + 4);
                    v8h hx = { (_Float16)x0.x, (_Float16)x0.y, (_Float16)x0.z, (_Float16)x0.w,
                               (_Float16)x1.x, (_Float16)x1.y, (_Float16)x1.z, (_Float16)x1.w };
                    af[kk] = hx;
                }
            }
            // h part (kb < 512): sentinel-poll into registers. Only l16<8
            // lanes retry (rows 8-15 are duplicates, loaded once).
            {
                const u64* hrow = (const u64*)((const _Float16*)hslab
                                  + ((size_t)t*32 + bb)*512);
                bool retry = true;
                while (retry) {
                    bool bad = false;
#pragma unroll
                    for (int kk = 0; kk < 6; ++kk) {
                        const int kb = (wave*6 + kk)*32 + quad*8;
                        if (kb < 512) {
                            const u64 w0 = AT_LD(hrow + (kb >> 2));
                            const u64 w1 = AT_LD(hrow + (kb >> 2) + 1);
                            bad = bad || has_ffff(w0) || has_ffff(w1);
                            af[kk] = __builtin_bit_cast(v8h, u64x2{w0, w1});
                        }
                    }
                    retry = bad && (l16 < 8);
                    if (retry) __builtin_amdgcn_s_sleep(1);
                }
            }

            // ---- GEMM: gates[b(8 used)][n(64)] partials, K quarter = wave ----
            v4f acc[4];
#pragma unroll
            for (int nt = 0; nt < 4; ++nt) { v4f z = {0.f,0.f,0.f,0.f}; acc[nt] = z; }
#pragma unroll
            for (int kk = 0; kk < 6; ++kk)
#pragma unroll
                for (int nt = 0; nt < 4; ++nt)
                    acc[nt] = __builtin_amdgcn_mfma_f32_16x16x32_f16(af[kk], bfrag[nt][kk], acc[nt], 0, 0, 0);

            // K-partials: one v4f (4 consecutive b) per (lane, nt) into
            // [n][wave][b16] -- disjoint 4-bank spans, conflict-free.
#pragma unroll
            for (int nt = 0; nt < 4; ++nt)
                *(v4f*)(gbuf + (nt*16 + l16)*GSTR + wave*16 + quad*4) = acc[nt];
            __syncthreads();   // S_c: partials ready (only barrier per step)

            // activations: tid<128, one (b, c) each
            if (tid < 128) {
                float g[4];
#pragma unroll
                for (int gi = 0; gi < 4; ++gi) {
                    const float* row = gbuf + (gi*16 + ac)*GSTR + ab;
                    g[gi] = row[0] + row[16] + row[32] + row[48] + bia[gi];
                }
                const float ig = 1.f/(1.f + __expf(-g[0]));
                const float fg = 1.f/(1.f + __expf(-g[1]));
                const float gg = 1.f - 2.f/(__expf(2.f*g[2]) + 1.f);
                const float og = 1.f/(1.f + __expf(-g[3]));
                cst = fg*cst + ig*gg;
                const float hn = og * (1.f - 2.f/(__expf(2.f*cst) + 1.f));
                const unsigned hb = (unsigned)__builtin_bit_cast(unsigned short, (_Float16)hn);
                const unsigned ot = (unsigned)__shfl_xor((int)hb, 1);
                if ((ac & 1) == 0) {
                    _Float16* hrow = (_Float16*)hslab
                        + ((size_t)(t+1)*32 + (grp*8 + ab))*512 + col0 + ac;
                    AT_ST((unsigned*)hrow, hb | (ot << 16));
                }
            }
            // no trailing barrier: double-buffered gates + next step's poll
        }
    }

    // join before epilogue
    __syncthreads();
    if (tid == 0) {
        __hip_atomic_fetch_add(cnts + 0, 1u, __ATOMIC_RELAXED, __HIP_MEMORY_SCOPE_AGENT);
        while (AT_LD(cnts + 0) < 128u) __builtin_amdgcn_s_sleep(8);
    }
    __syncthreads();

    // ---------------- collapsed attention epilogue ----------------
    // 4 pairs per WG: p = wgid*4+pp -> (b = p>>4, r = p&15, s' = 496+r)
    float*    hv  = (float*)smem;                 // [4][1024]
    _Float16* k16 = (_Float16*)(smem + 16384);    // [4][1024]
    float*    qb  = (float*)(smem + 24576);       // [4][64]
    float*    vzb = (float*)(smem + 25600);       // [4][16]
    float*    scb = (float*)(smem + 25856);       // [4][16]
    int*      lastf = (int*)(smem + 26112);

    const _Float16* WkT = (const _Float16*)(ws + OFF_WKT);
    const _Float16* WqT = (const _Float16*)(ws + OFF_WQT);
    const float* wv2 = (const float*)(ws + OFF_WV2);
    const float* cv  = (const float*)(ws + OFF_CV);
    const float* beff= (const float*)(ws + OFF_BEFF);

    const int p0 = wgid * 4;
#pragma unroll
    for (int i = 0; i < 4; ++i) {
        const int ch = tid + 256*i;               // 1024 u64 chunks
        const int pp = ch >> 8, q = ch & 255;     // e = q*4
        const int p = p0 + pp; const int b = p >> 4; const int r = p & 15;
        u64 w;
        if (q < 128)   // fwd h at s=496+r -> slot 497+r
            w = AT_LD((const u64*)(ws + OFF_HF) + ((size_t)(497 + r)*32 + b)*128 + q);
        else           // bwd h at s=496+r -> slot 16-r
            w = AT_LD((const u64*)(ws + OFF_HB) + ((size_t)(16 - r)*32 + b)*128 + (q - 128));
        float* dst = hv + pp*1024 + q*4;
#pragma unroll
        for (int j = 0; j < 4; ++j)
            dst[j] = (float)__builtin_bit_cast(_Float16, (unsigned short)((w >> (16*j)) & 0xFFFF));
    }
    __syncthreads();

    // K projection: k[pp][j], j = jj*256+tid
    float kacc[4][4];
#pragma unroll
    for (int jj = 0; jj < 4; ++jj) {
        const float bkv = bk[jj*256 + tid];
#pragma unroll
        for (int pp = 0; pp < 4; ++pp) kacc[jj][pp] = bkv;
    }
    for (int e = 0; e < 1024; ++e) {
        float hvv[4];
#pragma unroll
        for (int pp = 0; pp < 4; ++pp) hvv[pp] = hv[pp*1024 + e];
#pragma unroll
        for (int jj = 0; jj < 4; ++jj) {
            const float w = (float)WkT[(size_t)e*1024 + jj*256 + tid];
#pragma unroll
            for (int pp = 0; pp < 4; ++pp) kacc[jj][pp] += w * hvv[pp];
        }
    }
#pragma unroll
    for (int jj = 0; jj < 4; ++jj)
#pragma unroll
        for (int pp = 0; pp < 4; ++pp)
            k16[pp*1024 + jj*256 + tid] = (_Float16)kacc[jj][pp];

    // Q head 15: one pair per 64-lane chunk
    {
        const int d = tid & 63, ph = tid >> 6;
        float a0 = bq[960 + d];
        for (int e = 0; e < 1024; ++e)
            a0 += (float)WqT[e*64 + d] * hv[ph*1024 + e];
        qb[ph*64 + d] = a0;
    }
    // vz[pp][kh]
    if (tid < 64) {
        const int pp = tid >> 4, kh = tid & 15;
        const int r = (p0 + pp) & 15;
        float a = cv[r*16 + kh];
        for (int e = 0; e < 1024; ++e)
            a += wv2[((size_t)r*1024 + e)*16 + kh] * hv[pp*1024 + e];
        vzb[pp*16 + kh] = a;
    }
    __syncthreads();
    if (tid < 64) {
        const int pp = tid >> 4, kh = tid & 15;
        float a = 0.f;
#pragma unroll
        for (int d = 0; d < 64; ++d)
            a += qb[pp*64 + d] * (float)k16[pp*1024 + kh*64 + d];
        scb[pp*16 + kh] = a * 0.125f;
    }
    __syncthreads();
    if (tid < 4) {
        const int base = tid*16;
        float m = scb[base];
        for (int kh = 1; kh < 16; ++kh) m = fmaxf(m, scb[base+kh]);
        float sum = 0.f, wz = 0.f;
        for (int kh = 0; kh < 16; ++kh) {
            const float pe = __expf(scb[base+kh] - m);
            sum += pe; wz += pe * vzb[base+kh];
        }
        atomicAdd(&logits[(p0 + tid) >> 4], wz / sum);
    }
    __syncthreads();
    if (tid == 0) {
        const unsigned old = __hip_atomic_fetch_add(cnts + 2, 1u, __ATOMIC_RELAXED, __HIP_MEMORY_SCOPE_AGENT);
        *lastf = (old == 127u) ? 1 : 0;
    }
    __syncthreads();
    if (*lastf) {
        if (tid < 32) {
            const float lg = AT_LD(logits + tid) + beff[0];
            out[tid] = 1.f/(1.f + __expf(-lg));
        }
    }
}

// -------------------- launcher --------------------

extern "C" void kernel_launch(void* const* d_in, const int* in_sizes, int n_in,
                              void* d_out, int out_size, void* d_ws, size_t ws_size,
                              hipStream_t stream)
{
    (void)in_sizes; (void)n_in; (void)out_size; (void)ws_size;
    const float* x    = (const float*)d_in[0];
    const float* Wihf = (const float*)d_in[1];
    const float* Whhf = (const float*)d_in[2];
    const float* b_f  = (const float*)d_in[3];
    const float* Wihb = (const float*)d_in[4];
    const float* Whhb = (const float*)d_in[5];
    const float* b_b  = (const float*)d_in[6];
    const float* Wq   = (const float*)d_in[7];
    const float* bq   = (const float*)d_in[8];
    const float* Wk   = (const float*)d_in[9];
    const float* bk   = (const float*)d_in[10];
    const float* Wv   = (const float*)d_in[11];
    const float* bv   = (const float*)d_in[12];
    const float* Wo   = (const float*)d_in[13];
    const float* bo   = (const float*)d_in[14];
    const float* Wfc  = (const float*)d_in[15];
    const float* bfc  = (const float*)d_in[16];
    char* ws = (char*)d_ws;
    float* out = (float*)d_out;

    // init: counters/logits/weff/beff + h slot0 = 0; history slots = 0xFFFF sentinel
    hipMemsetAsync(ws, 0, OFF_HF + 32768, stream);                      // cnts..h_f[0]
    hipMemsetAsync(ws + OFF_HF + 32768, 0xFF, 512ull*32768, stream);    // h_f[1..512]
    hipMemsetAsync(ws + OFF_HB, 0, 32768, stream);                      // h_b[0]
    hipMemsetAsync(ws + OFF_HB + 32768, 0xFF, 16ull*32768, stream);     // h_b[1..16]

    hipLaunchKernelGGL(k_convert, dim3(512), dim3(256), 0, stream, Whhf, Wihf, Whhb, Wihb, ws);
    hipLaunchKernelGGL(k_weff,    dim3(64),  dim3(256), 0, stream, Wfc, Wo, bo, bfc, ws);
    hipLaunchKernelGGL(k_wv2,     dim3(65),  dim3(256), 0, stream, Wv, bv, ws);
    hipLaunchKernelGGL(k_tk,      dim3(1024),dim3(256), 0, stream, Wk, ws);
    hipLaunchKernelGGL(k_tq,      dim3(256), dim3(256), 0, stream, Wq, ws);
    hipLaunchKernelGGL(bilstm_main, dim3(128), dim3(256), DYN_LDS, stream,
                       x, b_f, b_b, bq, bk, ws, out);
}

// Round 12
// 1525.719 us; speedup vs baseline: 1.8820x; 1.8820x over previous
//
#include <hip/hip_runtime.h>
#include <cstdint>
#include <cstddef>

// B=32, S=512, I=256, H=512, E=1024, NH=16, HD=64
// Structural collapse (verified): only attention head 15 at s in [496,512)
// reaches the FC head; backward LSTM needs only its first 16 steps; Wo/Wfc
// fold to w_eff; w_eff-contracted Wv folds to wv2.
//
// Round 10: halve the sync domain. R9 (direct-reg polling) regressed 55%
// (per-lane redundant polls, VALU 2x) while proving conflicts (4.7e6) are
// NOT the critical path. R8 remains best (1765us dispatch). Residual ~5000
// cyc/step attributed to straggler-max over 32 producer-WGs per group.
// This round: 8 groups x 4 batches x 16 col-WGs of 32 cols (same 128-WG
// grid, same exchange protocol, same R8 gather->LDS pipeline). Producers
// per group 32->16, poll volume per consumer 8KB->4KB. B-tile per WG =
// 768x128 (8 nt, bfrag 192 VGPR; occ 1 wave/SIMD, fine at 128 WGs/256
// CUs). Gates stored via R9's conflict-free v4f [n][wave][b] layout.

typedef _Float16 v8h __attribute__((ext_vector_type(8)));
typedef _Float16 v4h __attribute__((ext_vector_type(4)));
typedef float    v4f __attribute__((ext_vector_type(4)));
typedef unsigned long long u64;

#define AT_LD(p)     __hip_atomic_load((p), __ATOMIC_RELAXED, __HIP_MEMORY_SCOPE_AGENT)
#define AT_ST(p, v)  __hip_atomic_store((p), (v), __ATOMIC_RELAXED, __HIP_MEMORY_SCOPE_AGENT)

// ---- workspace layout (bytes) ----
static constexpr size_t OFF_CNT   = 0;        // 3 x u32: lstm-done, -, epi-done
static constexpr size_t OFF_LOGIT = 256;      // 32 f32
static constexpr size_t OFF_BEFF  = 512;      // 1 f32
static constexpr size_t OFF_WEFF  = 1024;     // 1024 f32
static constexpr size_t OFF_HF    = 8192;     // h_f[513][32][512] f16 (slot = s+1)
static constexpr size_t HF_BYTES  = 513ull*32768;
static constexpr size_t OFF_HB    = OFF_HF + HF_BYTES;   // h_b[17][32][512] f16
static constexpr size_t HB_BYTES  = 17ull*32768;
static constexpr size_t OFF_WHHF  = OFF_HB + HB_BYTES;   // 2048x512 f16
static constexpr size_t OFF_WIHF  = OFF_WHHF + 2048ull*512*2;
static constexpr size_t OFF_WHHB  = OFF_WIHF + 2048ull*256*2;
static constexpr size_t OFF_WIHB  = OFF_WHHB + 2048ull*512*2;
static constexpr size_t OFF_WKT   = OFF_WIHB + 2048ull*256*2;   // 1024x1024 f16
static constexpr size_t OFF_WQT   = OFF_WKT + 1024ull*1024*2;   // 1024x64 f16
static constexpr size_t OFF_WV2   = OFF_WQT + 1024ull*64*2;     // 16*1024*16 f32
static constexpr size_t OFF_CV    = OFF_WV2 + 16ull*1024*16*4;  // 256 f32
// total ~25.7 MiB

static constexpr int PSTR    = 776;                 // panel row stride (f16)
static constexpr int GSTR    = 68;                  // gates row stride (f32)
static constexpr int LDS_PANEL_B = 4*PSTR*2;        // 6208 (4 batch rows)
static constexpr int DYN_LDS = LDS_PANEL_B + 128*GSTR*4;  // 6208+34816 = 41024

__device__ __forceinline__ bool has_ffff(u64 w) {
    return ((w & 0xFFFFull) == 0xFFFFull) ||
           (((w >> 16) & 0xFFFFull) == 0xFFFFull) ||
           (((w >> 32) & 0xFFFFull) == 0xFFFFull) ||
           ((w >> 48) == 0xFFFFull);
}

// -------------------- prep kernels --------------------

__global__ void k_convert(const float* __restrict__ whhf, const float* __restrict__ wihf,
                          const float* __restrict__ whhb, const float* __restrict__ wihb,
                          char* __restrict__ ws)
{
    _Float16* o1 = (_Float16*)(ws + OFF_WHHF);
    _Float16* o2 = (_Float16*)(ws + OFF_WIHF);
    _Float16* o3 = (_Float16*)(ws + OFF_WHHB);
    _Float16* o4 = (_Float16*)(ws + OFF_WIHB);
    const int stride = gridDim.x * blockDim.x;
    for (int i = blockIdx.x*blockDim.x + threadIdx.x; i < 2048*512; i += stride) {
        o1[i] = (_Float16)whhf[i];
        o3[i] = (_Float16)whhb[i];
    }
    for (int i = blockIdx.x*blockDim.x + threadIdx.x; i < 2048*256; i += stride) {
        o2[i] = (_Float16)wihf[i];
        o4[i] = (_Float16)wihb[i];
    }
}

// weff[e2] += partial(Wfc . Wo[:,e2]); beff += partial(Wfc . bo) (+bfc once)
__global__ void k_weff(const float* __restrict__ Wfc, const float* __restrict__ Wo,
                       const float* __restrict__ bo, const float* __restrict__ bfc,
                       char* __restrict__ ws)
{
    float* weff = (float*)(ws + OFF_WEFF);
    float* beff = (float*)(ws + OFF_BEFF);
    const int bid = blockIdx.x;                 // 64 blocks
    const int e2 = (bid & 3)*256 + threadIdx.x;
    const int slab = bid >> 2;                  // 16 slabs of 64 e
    float a = 0.f;
    for (int e = slab*64; e < slab*64 + 64; ++e)
        a += Wfc[e] * Wo[(size_t)e*1024 + e2];
    atomicAdd(weff + e2, a);
    if ((bid & 3) == 0 && threadIdx.x < 64) {
        const int e = slab*64 + threadIdx.x;
        float b = Wfc[e]*bo[e];
        if (bid == 0 && threadIdx.x == 0) b += bfc[0];
        atomicAdd(beff, b);
    }
}

// wv2[(r*1024+e)*16+kh] = sum_hd weff[r*64+hd]*Wv[(kh*64+hd)*1024+e]; cv
__global__ void k_wv2(const float* __restrict__ Wv, const float* __restrict__ bv,
                      char* __restrict__ ws)
{
    const float* weff = (const float*)(ws + OFF_WEFF);
    float* wv2 = (float*)(ws + OFF_WV2);
    float* cv  = (float*)(ws + OFF_CV);
    const int bid = blockIdx.x;                 // 65 blocks
    if (bid < 64) {
        const int r = bid >> 2;
        const int e = (bid & 3)*256 + threadIdx.x;
        for (int kh = 0; kh < 16; ++kh) {
            float a = 0.f;
            for (int hd = 0; hd < 64; ++hd)
                a += weff[r*64 + hd] * Wv[((size_t)(kh*64 + hd))*1024 + e];
            wv2[((size_t)r*1024 + e)*16 + kh] = a;
        }
    } else {
        const int r2 = threadIdx.x >> 4, k2 = threadIdx.x & 15;
        float a = 0.f;
        for (int hd = 0; hd < 64; ++hd)
            a += weff[r2*64 + hd] * bv[k2*64 + hd];
        cv[threadIdx.x] = a;
    }
}

// WkT[e][j] = Wk[j][e], fp16
__global__ void k_tk(const float* __restrict__ Wk, char* __restrict__ ws)
{
    _Float16* WkT = (_Float16*)(ws + OFF_WKT);
    __shared__ float tile[32][33];
    const int jt = blockIdx.x & 31, et = blockIdx.x >> 5;   // 1024 blocks
    const int tx = threadIdx.x & 31, ty = threadIdx.x >> 5; // 32x8
    for (int i = 0; i < 4; ++i)
        tile[ty + 8*i][tx] = Wk[((size_t)(jt*32 + ty + 8*i))*1024 + et*32 + tx];
    __syncthreads();
    for (int i = 0; i < 4; ++i)
        WkT[((size_t)(et*32 + ty + 8*i))*1024 + jt*32 + tx] = (_Float16)tile[tx][ty + 8*i];
}

// WqT15[e][d] = Wq[960+d][e], fp16
__global__ void k_tq(const float* __restrict__ Wq, char* __restrict__ ws)
{
    _Float16* WqT = (_Float16*)(ws + OFF_WQT);
    const int gid = blockIdx.x*256 + threadIdx.x;  // 256 blocks
    const int d = gid & 63, e = gid >> 6;
    WqT[e*64 + d] = (_Float16)Wq[((size_t)(960 + d))*1024 + e];
}

// -------------------- main persistent kernel --------------------
// 128 WGs x 256 threads. group g = wgid>>4 (4 batches), colgroup = wgid&15
// (32 h-cols). Phase 0: bwd 16 steps; phase 1: fwd 512 steps. Sentinel
// data-polling (wave-cooperative gather -> LDS panel, as R8). Sync domain:
// 16 producer-WGs per group.

__global__ __launch_bounds__(256, 1)
void bilstm_main(const float* __restrict__ xg,
                 const float* __restrict__ b_f, const float* __restrict__ b_b,
                 const float* __restrict__ bq,  const float* __restrict__ bk,
                 char* __restrict__ ws, float* __restrict__ out)
{
    extern __shared__ char smem[];
    _Float16* panel = (_Float16*)smem;                   // [4][776]
    float* gates = (float*)(smem + LDS_PANEL_B);         // [128][68]

    const int tid  = threadIdx.x;
    const int wgid = blockIdx.x;
    const int wave = tid >> 6;
    const int lane = tid & 63;
    const int quad = lane >> 4;
    const int l16  = lane & 15;
    const int grp  = wgid >> 4;            // batch group (4 batches), 8 groups
    const int col0 = (wgid & 15) * 32;     // 16 col-groups of 32 cols

    unsigned* cnts  = (unsigned*)(ws + OFF_CNT);
    float*   logits = (float*)(ws + OFF_LOGIT);

    // activation role (tid < 128): batch b = tid>>5 in [0,4), col c = tid&31
    const int ac = tid & 31;
    const int ab = tid >> 5;

    for (int phase = 0; phase < 2; ++phase) {
        const int dir     = phase == 0 ? 1 : 0;       // bwd first
        const int nsteps  = dir ? 16 : 512;
        char* hslab = ws + (dir ? OFF_HB : OFF_HF);
        const _Float16* whh = (const _Float16*)(ws + (dir ? OFF_WHHB : OFF_WHHF));
        const _Float16* wih = (const _Float16*)(ws + (dir ? OFF_WIHB : OFF_WIHF));
        const float* bias = dir ? b_b : b_f;

        // persistent B fragments: 8 nt tiles x 6 kk, wave = K-quarter.
        // local row lr = nt*16+l16 -> gate g = lr>>5, col cc = lr&31,
        // global row r = g*512 + col0 + cc.
        v8h bfrag[8][6];
#pragma unroll
        for (int nt = 0; nt < 8; ++nt)
#pragma unroll
            for (int kk = 0; kk < 6; ++kk) {
                const int kb = (wave*6 + kk)*32 + quad*8;
                const int lr = nt*16 + l16;
                const int r  = (lr >> 5)*512 + col0 + (lr & 31);
                const _Float16* src = (kb < 512) ? (whh + (size_t)r*512 + kb)
                                                 : (wih + (size_t)r*256 + (kb - 512));
                bfrag[nt][kk] = *(const v8h*)src;
            }
        float bia[4];
#pragma unroll
        for (int g = 0; g < 4; ++g) bia[g] = bias[g*512 + col0 + ac];

        float cst = 0.f;

        for (int t = 0; t < nsteps; ++t) {
            const int s = dir ? (511 - t) : t;

            // prefetch x[4 batches][s][:] into registers (one float4/thread)
            const int xb = tid >> 6, xic = tid & 63;
            const float4 xv = *(const float4*)(xg
                + ((size_t)(grp*4 + xb)*512 + s)*256 + xic*4);

            // gather h_{t-1} (slot t): 4 KB = 4 b x 512 cols, 16B/thread.
            // b=tid&3, seg=tid>>2: LDS write banks 4(b+seg) mod 32 spread.
            {
                const int b = tid & 3, seg = tid >> 2;   // seg in [0,64)
                const u64* src = (const u64*)hslab
                    + (size_t)t*4096 + (size_t)(grp*4 + b)*128 + seg*2;
                u64 w0, w1;
                for (;;) {
                    w0 = AT_LD(src + 0); w1 = AT_LD(src + 1);
                    if (!(has_ffff(w0) || has_ffff(w1)))
                        break;
                    __builtin_amdgcn_s_sleep(1);
                }
                u64* dst = (u64*)(panel + b*PSTR + seg*8);
                dst[0] = w0; dst[1] = w1;
            }
            // x (f32 regs -> f16) into panel cols [512,768)
            {
                v4h hx = { (_Float16)xv.x, (_Float16)xv.y,
                           (_Float16)xv.z, (_Float16)xv.w };
                *(v4h*)(panel + xb*PSTR + 512 + xic*4) = hx;
            }
            __syncthreads();   // S_a: panel ready

            // GEMM: gates[b(4 used of 16)][n(128)] = A[b][768] * W[n][768]
            // A row m = l16, batch = l16&3 (rows 4-15 duplicates, discarded).
            v4f acc[8];
#pragma unroll
            for (int nt = 0; nt < 8; ++nt) { v4f z = {0.f,0.f,0.f,0.f}; acc[nt] = z; }
#pragma unroll
            for (int kk = 0; kk < 6; ++kk) {
                const int kb = (wave*6 + kk)*32 + quad*8;
                const v8h a0 = *(const v8h*)(panel + (l16 & 3)*PSTR + kb);
#pragma unroll
                for (int nt = 0; nt < 8; ++nt)
                    acc[nt] = __builtin_amdgcn_mfma_f32_16x16x32_f16(a0, bfrag[nt][kk], acc[nt], 0, 0, 0);
            }
            // K-partials: one v4f per (lane, nt) into [lr][wave*16 + m],
            // m = quad*4+r = C row; activation reads m = b in [0,4).
#pragma unroll
            for (int nt = 0; nt < 8; ++nt)
                *(v4f*)(gates + (nt*16 + l16)*GSTR + wave*16 + quad*4) = acc[nt];
            __syncthreads();   // S_c: partials ready

            // activations: tid<128, one (b in [0,4), c in [0,32)) each
            if (tid < 128) {
                float g[4];
#pragma unroll
                for (int gi = 0; gi < 4; ++gi) {
                    const float* row = gates + (gi*32 + ac)*GSTR + ab;
                    g[gi] = row[0] + row[16] + row[32] + row[48] + bia[gi];
                }
                const float ig = 1.f/(1.f + __expf(-g[0]));
                const float fg = 1.f/(1.f + __expf(-g[1]));
                const float gg = 1.f - 2.f/(__expf(2.f*g[2]) + 1.f);
                const float og = 1.f/(1.f + __expf(-g[3]));
                cst = fg*cst + ig*gg;
                const float hn = og * (1.f - 2.f/(__expf(2.f*cst) + 1.f));
                const unsigned hb = (unsigned)__builtin_bit_cast(unsigned short, (_Float16)hn);
                const unsigned ot = (unsigned)__shfl_xor((int)hb, 1);
                if ((ac & 1) == 0) {
                    _Float16* hrow = (_Float16*)hslab
                        + ((size_t)(t+1)*32 + (grp*4 + ab))*512 + col0 + ac;
                    AT_ST((unsigned*)hrow, hb | (ot << 16));
                }
            }
            // no trailing barrier: next step's poll + S_a self-synchronize
        }
    }

    // join before epilogue
    __syncthreads();
    if (tid == 0) {
        __hip_atomic_fetch_add(cnts + 0, 1u, __ATOMIC_RELAXED, __HIP_MEMORY_SCOPE_AGENT);
        while (AT_LD(cnts + 0) < 128u) __builtin_amdgcn_s_sleep(8);
    }
    __syncthreads();

    // ---------------- collapsed attention epilogue ----------------
    // 4 pairs per WG: p = wgid*4+pp -> (b = p>>4, r = p&15, s' = 496+r)
    float*    hv  = (float*)smem;                 // [4][1024]
    _Float16* k16 = (_Float16*)(smem + 16384);    // [4][1024]
    float*    qb  = (float*)(smem + 24576);       // [4][64]
    float*    vzb = (float*)(smem + 25600);       // [4][16]
    float*    scb = (float*)(smem + 25856);       // [4][16]
    int*      lastf = (int*)(smem + 26112);

    const _Float16* WkT = (const _Float16*)(ws + OFF_WKT);
    const _Float16* WqT = (const _Float16*)(ws + OFF_WQT);
    const float* wv2 = (const float*)(ws + OFF_WV2);
    const float* cv  = (const float*)(ws + OFF_CV);
    const float* beff= (const float*)(ws + OFF_BEFF);

    const int p0 = wgid * 4;
#pragma unroll
    for (int i = 0; i < 4; ++i) {
        const int ch = tid + 256*i;               // 1024 u64 chunks
        const int pp = ch >> 8, q = ch & 255;     // e = q*4
        const int p = p0 + pp; const int b = p >> 4; const int r = p & 15;
        u64 w;
        if (q < 128)   // fwd h at s=496+r -> slot 497+r
            w = AT_LD((const u64*)(ws + OFF_HF) + ((size_t)(497 + r)*32 + b)*128 + q);
        else           // bwd h at s=496+r -> slot 16-r
            w = AT_LD((const u64*)(ws + OFF_HB) + ((size_t)(16 - r)*32 + b)*128 + (q - 128));
        float* dst = hv + pp*1024 + q*4;
#pragma unroll
        for (int j = 0; j < 4; ++j)
            dst[j] = (float)__builtin_bit_cast(_Float16, (unsigned short)((w >> (16*j)) & 0xFFFF));
    }
    __syncthreads();

    // K projection: k[pp][j], j = jj*256+tid
    float kacc[4][4];
#pragma unroll
    for (int jj = 0; jj < 4; ++jj) {
        const float bkv = bk[jj*256 + tid];
#pragma unroll
        for (int pp = 0; pp < 4; ++pp) kacc[jj][pp] = bkv;
    }
    for (int e = 0; e < 1024; ++e) {
        float hvv[4];
#pragma unroll
        for (int pp = 0; pp < 4; ++pp) hvv[pp] = hv[pp*1024 + e];
#pragma unroll
        for (int jj = 0; jj < 4; ++jj) {
            const float w = (float)WkT[(size_t)e*1024 + jj*256 + tid];
#pragma unroll
            for (int pp = 0; pp < 4; ++pp) kacc[jj][pp] += w * hvv[pp];
        }
    }
#pragma unroll
    for (int jj = 0; jj < 4; ++jj)
#pragma unroll
        for (int pp = 0; pp < 4; ++pp)
            k16[pp*1024 + jj*256 + tid] = (_Float16)kacc[jj][pp];

    // Q head 15: one pair per 64-lane chunk
    {
        const int d = tid & 63, ph = tid >> 6;
        float a0 = bq[960 + d];
        for (int e = 0; e < 1024; ++e)
            a0 += (float)WqT[e*64 + d] * hv[ph*1024 + e];
        qb[ph*64 + d] = a0;
    }
    // vz[pp][kh]
    if (tid < 64) {
        const int pp = tid >> 4, kh = tid & 15;
        const int r = (p0 + pp) & 15;
        float a = cv[r*16 + kh];
        for (int e = 0; e < 1024; ++e)
            a += wv2[((size_t)r*1024 + e)*16 + kh] * hv[pp*1024 + e];
        vzb[pp*16 + kh] = a;
    }
    __syncthreads();
    if (tid < 64) {
        const int pp = tid >> 4, kh = tid & 15;
        float a = 0.f;
#pragma unroll
        for (int d = 0; d < 64; ++d)
            a += qb[pp*64 + d] * (float)k16[pp*1024 + kh*64 + d];
        scb[pp*16 + kh] = a * 0.125f;
    }
    __syncthreads();
    if (tid < 4) {
        const int base = tid*16;
        float m = scb[base];
        for (int kh = 1; kh < 16; ++kh) m = fmaxf(m, scb[base+kh]);
        float sum = 0.f, wz = 0.f;
        for (int kh = 0; kh < 16; ++kh) {
            const float pe = __expf(scb[base+kh] - m);
            sum += pe; wz += pe * vzb[base+kh];
        }
        atomicAdd(&logits[(p0 + tid) >> 4], wz / sum);
    }
    __syncthreads();
    if (tid == 0) {
        const unsigned old = __hip_atomic_fetch_add(cnts + 2, 1u, __ATOMIC_RELAXED, __HIP_MEMORY_SCOPE_AGENT);
        *lastf = (old == 127u) ? 1 : 0;
    }
    __syncthreads();
    if (*lastf) {
        if (tid < 32) {
            const float lg = AT_LD(logits + tid) + beff[0];
            out[tid] = 1.f/(1.f + __expf(-lg));
        }
    }
}

// -------------------- launcher --------------------

extern "C" void kernel_launch(void* const* d_in, const int* in_sizes, int n_in,
                              void* d_out, int out_size, void* d_ws, size_t ws_size,
                              hipStream_t stream)
{
    (void)in_sizes; (void)n_in; (void)out_size; (void)ws_size;
    const float* x    = (const float*)d_in[0];
    const float* Wihf = (const float*)d_in[1];
    const float* Whhf = (const float*)d_in[2];
    const float* b_f  = (const float*)d_in[3];
    const float* Wihb = (const float*)d_in[4];
    const float* Whhb = (const float*)d_in[5];
    const float* b_b  = (const float*)d_in[6];
    const float* Wq   = (const float*)d_in[7];
    const float* bq   = (const float*)d_in[8];
    const float* Wk   = (const float*)d_in[9];
    const float* bk   = (const float*)d_in[10];
    const float* Wv   = (const float*)d_in[11];
    const float* bv   = (const float*)d_in[12];
    const float* Wo   = (const float*)d_in[13];
    const float* bo   = (const float*)d_in[14];
    const float* Wfc  = (const float*)d_in[15];
    const float* bfc  = (const float*)d_in[16];
    char* ws = (char*)d_ws;
    float* out = (float*)d_out;

    // init: counters/logits/weff/beff + h slot0 = 0; history slots = 0xFFFF sentinel
    hipMemsetAsync(ws, 0, OFF_HF + 32768, stream);                      // cnts..h_f[0]
    hipMemsetAsync(ws + OFF_HF + 32768, 0xFF, 512ull*32768, stream);    // h_f[1..512]
    hipMemsetAsync(ws + OFF_HB, 0, 32768, stream);                      // h_b[0]
    hipMemsetAsync(ws + OFF_HB + 32768, 0xFF, 16ull*32768, stream);     // h_b[1..16]

    hipLaunchKernelGGL(k_convert, dim3(512), dim3(256), 0, stream, Whhf, Wihf, Whhb, Wihb, ws);
    hipLaunchKernelGGL(k_weff,    dim3(64),  dim3(256), 0, stream, Wfc, Wo, bo, bfc, ws);
    hipLaunchKernelGGL(k_wv2,     dim3(65),  dim3(256), 0, stream, Wv, bv, ws);
    hipLaunchKernelGGL(k_tk,      dim3(1024),dim3(256), 0, stream, Wk, ws);
    hipLaunchKernelGGL(k_tq,      dim3(256), dim3(256), 0, stream, Wq, ws);
    hipLaunchKernelGGL(bilstm_main, dim3(128), dim3(256), DYN_LDS, stream,
                       x, b_f, b_b, bq, bk, ws, out);
}